// Round 8
// baseline (3092.122 us; speedup 1.0000x reference)
//
#include <hip/hip_runtime.h>

typedef _Float16 half8 __attribute__((ext_vector_type(8)));
typedef _Float16 half4 __attribute__((ext_vector_type(4)));
typedef float    f32x4 __attribute__((ext_vector_type(4)));

#define N_NODES 65536
#define N_EDGES 131072
#define BB      2048
#define HDIM    300
#define HPAD    320   // K padded to multiple of 32

// aux layout (ints): [0:16) dhist, [16:32) dbase, [32:48) ebase, [48:64) dcnt, [64] e15
#define A_DHIST 0
#define A_DBASE 16
#define A_EBASE 32
#define A_DCNT  48
#define A_E15   64

// ---------------- prepack: dst[384][Kpad] = W[k][n]  (B^T panel, zero-padded)
__global__ __launch_bounds__(256) void prepack_w(const float* __restrict__ src,
                                                 _Float16* __restrict__ dst,
                                                 int Kpad, int Kreal) {
    int idx = blockIdx.x * 256 + threadIdx.x;
    int n = idx / Kpad, k = idx - n * Kpad;
    if (n >= 384) return;
    float v = (n < 300 && k < Kreal) ? src[k * 300 + n] : 0.f;
    dst[idx] = (_Float16)v;
}

__global__ __launch_bounds__(256) void cvt_x(const float* __restrict__ x,
                                             _Float16* __restrict__ xh, int n) {
    int i = blockIdx.x * 256 + threadIdx.x;
    if (i < n) xh[i] = (_Float16)x[i];
}

// edge feats -> f16, permuted into CSR order, zero-padded to 32 cols
__global__ __launch_bounds__(256) void cvt_e_csr(const float* __restrict__ ein,
                                                 const int2* __restrict__ se,
                                                 _Float16* __restrict__ ecsr) {
    int i = blockIdx.x * 256 + threadIdx.x;
    if (i >= N_EDGES * 32) return;
    int k = i & 31, s = i >> 5;
    int e = se[s].y;
    ecsr[i] = (_Float16)(k < 16 ? ein[(size_t)e * 16 + k] : 0.f);
}

__device__ __forceinline__ void gload16(const _Float16* g, _Float16* l) {
    __builtin_amdgcn_global_load_lds(
        (const __attribute__((address_space(1))) void*)g,
        (__attribute__((address_space(3))) void*)l, 16, 0, 0);
}

// ---------------- MFMA GEMM: out[M][320] = op( A[M][K] @ Bp^T ) + bias
// Bp is [384][K] f16. 128x128 tile, 4 waves, 64x64/wave.
// global_load_lds staging, 3-buf, SINGLE barrier per K-iter, counted vmcnt,
// XOR-swizzled LDS, XCD-grouped blocks, LDS-transposed coalesced epilogue.
template <bool RELU>
__global__ __launch_bounds__(256) void gemm_f16(
        const _Float16* __restrict__ A,
        const _Float16* __restrict__ Bp, const float* __restrict__ bias,
        _Float16* __restrict__ out, int M, int K) {
    __shared__ _Float16 lds[3][2][128 * 32];   // [buf][A/B][row*32+k] : 48 KB

    // XCD grouping: the 3 nt-siblings of one mt land on the same XCD (bid%8)
    int bid = blockIdx.x;
    int xcd = bid & 7, grp = bid >> 3;
    int mt = xcd + 8 * (grp / 3);
    int nt = grp % 3;
    int m0 = mt * 128, n0 = nt * 128;
    int t = threadIdx.x;
    int lane = t & 63, w = t >> 6;
    int wr = w >> 1, wc = w & 1;

    // staging geometry: wave w stages 2 chunks of 16 rows each (1 KB per inst)
    // LDS slot (row, lane&3) <- global chunk (lane&3) ^ ((row>>1)&3)
    int srow[2], sko[2];
    #pragma unroll
    for (int q = 0; q < 2; ++q) {
        int row = (w * 2 + q) * 16 + (lane >> 2);
        int ch = (lane & 3) ^ ((row >> 1) & 3);
        srow[q] = row; sko[q] = ch * 8;
    }

    f32x4 acc[4][4] = {};
    int NK = K >> 5;

    auto stage = [&](int buf, int k0) {
        #pragma unroll
        for (int q = 0; q < 2; ++q) {
            gload16(&A[(size_t)(m0 + srow[q]) * K + k0 + sko[q]], &lds[buf][0][(w * 2 + q) * 512]);
            gload16(&Bp[(size_t)(n0 + srow[q]) * K + k0 + sko[q]], &lds[buf][1][(w * 2 + q) * 512]);
        }
    };

    stage(0, 0);
    if (NK > 1) stage(1, 32);
    for (int kt = 0; kt < NK; ++kt) {
        int cur = kt % 3;
        if (kt + 1 < NK) {
            asm volatile("s_waitcnt vmcnt(4)" ::: "memory");   // stage kt landed
        } else {
            asm volatile("s_waitcnt vmcnt(0)" ::: "memory");
        }
        __builtin_amdgcn_s_barrier();
        __builtin_amdgcn_sched_barrier(0);
        if (kt + 2 < NK) stage((kt + 2) % 3, (kt + 2) << 5);

        int lr = lane & 15, hi = lane >> 4;
        half8 af[4], bf[4];
        #pragma unroll
        for (int i = 0; i < 4; ++i) {
            int row = wr * 64 + i * 16 + lr;
            int lk = (hi ^ ((row >> 1) & 3)) * 8;
            af[i] = *(const half8*)&lds[cur][0][row * 32 + lk];
        }
        #pragma unroll
        for (int j = 0; j < 4; ++j) {
            int row = wc * 64 + j * 16 + lr;
            int lk = (hi ^ ((row >> 1) & 3)) * 8;
            bf[j] = *(const half8*)&lds[cur][1][row * 32 + lk];
        }
        #pragma unroll
        for (int i = 0; i < 4; ++i)
            #pragma unroll
            for (int j = 0; j < 4; ++j)
                acc[i][j] = __builtin_amdgcn_mfma_f32_16x16x32_f16(af[i], bf[j], acc[i][j], 0, 0, 0);
    }
    __syncthreads();   // protect lds reuse by epilogue

    // epilogue: acc -> LDS (f16, 128x128) -> coalesced 256B stores
    _Float16* ct = &lds[0][0][0];
    {
        int lr = lane & 15, lq = (lane >> 4) * 4;
        #pragma unroll
        for (int j = 0; j < 4; ++j) {
            int col = wc * 64 + j * 16 + lr;
            int gcol = n0 + col;
            float bv = (gcol < 300) ? bias[gcol] : 0.f;
            #pragma unroll
            for (int i = 0; i < 4; ++i) {
                int rbase = wr * 64 + i * 16 + lq;
                #pragma unroll
                for (int q = 0; q < 4; ++q) {
                    float v = acc[i][j][q] + bv;
                    if (RELU) v = v > 0.f ? v : 0.f;
                    if (gcol >= 300) v = 0.f;
                    ct[(rbase + q) * 128 + col] = (_Float16)v;
                }
            }
        }
    }
    __syncthreads();
    #pragma unroll
    for (int r = 0; r < 8; ++r) {
        int row = r * 16 + (t >> 4);
        int c8 = (t & 15) * 8;
        if (n0 + c8 < HPAD) {
            half8 v = *(const half8*)&ct[row * 128 + c8];
            *(half8*)&out[(size_t)(m0 + row) * HPAD + n0 + c8] = v;
        }
    }
}

// ---------------- CSR build with degree-sorted node order ----------------
__global__ __launch_bounds__(256) void hist_kernel(const int* __restrict__ dst,
                                                   int* __restrict__ counts) {
    int e = blockIdx.x * 256 + threadIdx.x;
    if (e < N_EDGES) atomicAdd(&counts[dst[e]], 1);
}

__global__ __launch_bounds__(256) void bucket_hist(const int* __restrict__ counts,
                                                   int* __restrict__ aux) {
    int n = blockIdx.x * 256 + threadIdx.x;
    if (n >= N_NODES) return;
    int b = counts[n]; b = b < 15 ? b : 15;
    atomicAdd(&aux[A_DHIST + b], 1);
}

__global__ void scan16(int* __restrict__ aux) {
    if (threadIdx.x == 0) {
        int acc = 0, eacc = 0;
        for (int b = 0; b < 15; ++b) {
            aux[A_DBASE + b] = acc;
            aux[A_EBASE + b] = eacc;
            acc  += aux[A_DHIST + b];
            eacc += aux[A_DHIST + b] * b;
        }
        aux[A_DBASE + 15] = acc;
        aux[A_EBASE + 15] = eacc;
    }
}

// place nodes into degree-sorted order; emit per-sorted-slot (r0,deg) and per-node r0
__global__ __launch_bounds__(256) void place_nodes(const int* __restrict__ counts,
                                                   int* __restrict__ aux,
                                                   int* __restrict__ sortedid,
                                                   int2* __restrict__ rptr,
                                                   int* __restrict__ r0node) {
    int n = blockIdx.x * 256 + threadIdx.x;
    if (n >= N_NODES) return;
    int deg = counts[n];
    int b = deg < 15 ? deg : 15;
    int pos = atomicAdd(&aux[A_DCNT + b], 1);
    int i = aux[A_DBASE + b] + pos;
    int r0;
    if (b < 15) r0 = aux[A_EBASE + b] + pos * b;
    else        r0 = aux[A_EBASE + 15] + atomicAdd(&aux[A_E15], deg);
    sortedid[i] = n;
    rptr[i] = make_int2(r0, deg);
    r0node[n] = r0;
}

__global__ __launch_bounds__(256) void scatter_csr(const int* __restrict__ src,
                                                   const int* __restrict__ dst,
                                                   const int* __restrict__ r0node,
                                                   int* __restrict__ cnt,
                                                   int2* __restrict__ se) {
    int e = blockIdx.x * 256 + threadIdx.x;
    if (e >= N_EDGES) return;
    int d = dst[e];
    int pos = atomicAdd(&cnt[d], 1);
    se[r0node[d] + pos] = make_int2(src[e], e);
}

// ---------------- gather: z[d] = h[d] + sum_{s in row(d)} relu(h[src_s] + ehcsr[s])
// Nodes processed in degree-sorted order: all 8 node-slots of a wave-group have
// (nearly) equal degree -> no trip-count divergence. 320 thr = 8 slots x 40 half8.
__global__ __launch_bounds__(320) void gather_z(
        const _Float16* __restrict__ h, const _Float16* __restrict__ ehcsr,
        const int2* __restrict__ se, const int* __restrict__ sortedid,
        const int2* __restrict__ rptr, _Float16* __restrict__ z, int nblocks) {
    int t = threadIdx.x;
    int c = t % 40, ns = t / 40;
    for (int i = blockIdx.x * 8 + ns; i < N_NODES; i += nblocks * 8) {
        int node = sortedid[i];
        int2 rr = rptr[i];
        int r0 = rr.x, r1 = rr.x + rr.y;
        half8 hn = *(const half8*)&h[(size_t)node * HPAD + c * 8];
        half8 acc = {};
        for (int s = r0; s < r1; s += 4) {
            int nb = r1 - s;
            int idx[4];
            idx[0] = s;
            idx[1] = s + (1 < nb ? 1 : 0);
            idx[2] = s + (2 < nb ? 2 : 0);
            idx[3] = s + (3 < nb ? 3 : 0);
            half8 hv[4], ev[4];
            #pragma unroll
            for (int u = 0; u < 4; ++u) {
                int sp = se[idx[u]].x;
                hv[u] = *(const half8*)&h[(size_t)sp * HPAD + c * 8];
                ev[u] = *(const half8*)&ehcsr[(size_t)idx[u] * HPAD + c * 8];
            }
            #pragma unroll
            for (int u = 0; u < 4; ++u) {
                half8 m = hv[u] + ev[u];
                #pragma unroll
                for (int j = 0; j < 8; ++j)
                    m[j] = m[j] > (_Float16)0 ? m[j] : (_Float16)0;
                if (u < nb) acc += m;
            }
        }
        half8 o = hn + acc;          // pad cols: 0 + 0 = 0
        *(half8*)&z[(size_t)node * HPAD + c * 8] = o;
    }
}

// ---------------- per-molecule sum pool (32 consecutive rows)
__global__ __launch_bounds__(128) void pool_kernel(const _Float16* __restrict__ h,
                                                   float* __restrict__ out, int add) {
    int b = blockIdx.x, t = threadIdx.x;
    if (t >= 75) return;
    float a0 = 0, a1 = 0, a2 = 0, a3 = 0;
    for (int r = 0; r < 32; ++r) {
        half4 v = *(const half4*)&h[(size_t)(b * 32 + r) * HPAD + t * 4];
        a0 += (float)v[0]; a1 += (float)v[1]; a2 += (float)v[2]; a3 += (float)v[3];
    }
    f32x4 o = {a0, a1, a2, a3};
    if (add) o += *(f32x4*)&out[b * 300 + t * 4];
    *(f32x4*)&out[b * 300 + t * 4] = o;
}

__global__ __launch_bounds__(256) void diff_kernel(float* __restrict__ reaction,
                                                   const float* __restrict__ reactants,
                                                   const float* __restrict__ products, int n) {
    int i = blockIdx.x * 256 + threadIdx.x;
    if (i < n) reaction[i] = reactants[i] - products[i];
}

extern "C" void kernel_launch(void* const* d_in, const int* in_sizes, int n_in,
                              void* d_out, int out_size, void* d_ws, size_t ws_size,
                              hipStream_t stream) {
    const float* x[3]   = {(const float*)d_in[0], (const float*)d_in[5],  (const float*)d_in[10]};
    const float* ein[3] = {(const float*)d_in[1], (const float*)d_in[6],  (const float*)d_in[11]};
    const int*   src[3] = {(const int*)d_in[2],   (const int*)d_in[7],    (const int*)d_in[12]};
    const int*   dst[3] = {(const int*)d_in[3],   (const int*)d_in[8],    (const int*)d_in[13]};
    const float* Wn = (const float*)d_in[15];
    const float* bn = (const float*)d_in[16];
    const float* We = (const float*)d_in[17];
    const float* be = (const float*)d_in[18];
    const float* W1 = (const float*)d_in[19];
    const float* b1 = (const float*)d_in[20];
    const float* W2 = (const float*)d_in[21];
    const float* b2 = (const float*)d_in[22];

    char* ws = (char*)d_ws;
    size_t off = 0;
    auto alloc = [&](size_t bytes) {
        char* p = ws + off; off += (bytes + 1023) & ~(size_t)1023; return p;
    };
    _Float16* h     = (_Float16*)alloc((size_t)N_NODES * HPAD * 2);   // 40 MiB
    _Float16* zbuf  = (_Float16*)alloc((size_t)N_NODES * HPAD * 2);   // 40 MiB
    _Float16* tbuf  = (_Float16*)alloc((size_t)N_NODES * HPAD * 2);   // 40 MiB
    _Float16* ehcsr = (_Float16*)alloc((size_t)N_EDGES * HPAD * 2);   // 80 MiB
    int*      counts= (int*)alloc((size_t)N_NODES * 4);               // \ contiguous
    int*      cnt   = (int*)alloc((size_t)N_NODES * 4);               //  | memset
    int*      aux   = (int*)alloc(256 * 4);                           // /  region
    int*      sortedid = (int*)alloc((size_t)N_NODES * 4);
    int2*     rptr  = (int2*)alloc((size_t)N_NODES * 8);
    int*      r0node= (int*)alloc((size_t)N_NODES * 4);
    int2*     se    = (int2*)alloc((size_t)N_EDGES * 8);
    _Float16* Wt1   = (_Float16*)alloc((size_t)3 * 384 * HPAD * 2);
    _Float16* Wt2   = (_Float16*)alloc((size_t)3 * 384 * HPAD * 2);
    _Float16* Wnt   = (_Float16*)alloc((size_t)384 * 64 * 2);
    _Float16* Wet   = (_Float16*)alloc((size_t)384 * 32 * 2);
    // overlays (both dead before their hosts are written):
    _Float16* xh    = (_Float16*)zbuf;   // consumed by node-proj GEMM before gather writes zbuf
    _Float16* ecsr  = (_Float16*)tbuf;   // consumed by eh-GEMM before GEMM1 writes tbuf

    if (off > ws_size) return;   // graceful diagnostic failure if ws too small

    for (int l = 0; l < 3; ++l) {
        prepack_w<<<(384 * HPAD + 255) / 256, 256, 0, stream>>>(W1 + l * 90000, Wt1 + l * 384 * HPAD, HPAD, 300);
        prepack_w<<<(384 * HPAD + 255) / 256, 256, 0, stream>>>(W2 + l * 90000, Wt2 + l * 384 * HPAD, HPAD, 300);
    }
    prepack_w<<<(384 * 64 + 255) / 256, 256, 0, stream>>>(Wn, Wnt, 64, 64);
    prepack_w<<<(384 * 32 + 255) / 256, 256, 0, stream>>>(We, Wet, 32, 16);

    float* outp      = (float*)d_out;
    float* reaction  = outp;
    float* reactants = outp + (size_t)BB * HDIM;
    float* products  = outp + (size_t)2 * BB * HDIM;

    const int EG = (N_EDGES + 255) / 256;
    const int NG = (N_NODES + 255) / 256;
    for (int g = 0; g < 3; ++g) {
        // node projection: h = relu(x @ Wn + bn)
        cvt_x<<<(N_NODES * 64 + 255) / 256, 256, 0, stream>>>(x[g], xh, N_NODES * 64);
        gemm_f16<true><<<512 * 3, 256, 0, stream>>>(xh, Wnt, bn, h, N_NODES, 64);

        // degree-sorted CSR build (incoming edges per node)
        hipMemsetAsync(counts, 0, (size_t)(2 * N_NODES + 256) * 4, stream);  // counts+cnt+aux
        hist_kernel<<<EG, 256, 0, stream>>>(dst[g], counts);
        bucket_hist<<<NG, 256, 0, stream>>>(counts, aux);
        scan16<<<1, 64, 0, stream>>>(aux);
        place_nodes<<<NG, 256, 0, stream>>>(counts, aux, sortedid, rptr, r0node);
        scatter_csr<<<EG, 256, 0, stream>>>(src[g], dst[g], r0node, cnt, se);

        // edge projection once per graph, in CSR order: ehcsr = ecsr @ We + be
        cvt_e_csr<<<(N_EDGES * 32 + 255) / 256, 256, 0, stream>>>(ein[g], se, ecsr);
        gemm_f16<false><<<1024 * 3, 256, 0, stream>>>(ecsr, Wet, be, ehcsr, N_EDGES, 32);

        for (int l = 0; l < 3; ++l) {
            gather_z<<<2048, 320, 0, stream>>>(h, ehcsr, se, sortedid, rptr, zbuf, 2048);
            // t = relu(z @ W1[l] + b1[l])
            gemm_f16<true><<<512 * 3, 256, 0, stream>>>(zbuf, Wt1 + l * 384 * HPAD, b1 + l * 300, tbuf, N_NODES, HPAD);
            // h = t @ W2[l] + b2[l]  (+relu if l<2)
            if (l < 2)
                gemm_f16<true ><<<512 * 3, 256, 0, stream>>>(tbuf, Wt2 + l * 384 * HPAD, b2 + l * 300, h, N_NODES, HPAD);
            else
                gemm_f16<false><<<512 * 3, 256, 0, stream>>>(tbuf, Wt2 + l * 384 * HPAD, b2 + l * 300, h, N_NODES, HPAD);
        }
        if (g == 0)      pool_kernel<<<BB, 128, 0, stream>>>(h, reactants, 0);
        else if (g == 1) pool_kernel<<<BB, 128, 0, stream>>>(h, reactants, 1);
        else             pool_kernel<<<BB, 128, 0, stream>>>(h, products, 0);
    }
    diff_kernel<<<((BB * HDIM) + 255) / 256, 256, 0, stream>>>(reaction, reactants, products, BB * HDIM);
}

// Round 9
// 1112.055 us; speedup vs baseline: 2.7805x; 2.7805x over previous
//
#include <hip/hip_runtime.h>

typedef _Float16 half8 __attribute__((ext_vector_type(8)));
typedef _Float16 half4 __attribute__((ext_vector_type(4)));
typedef float    f32x4 __attribute__((ext_vector_type(4)));

#define N_NODES 65536
#define N_EDGES 131072
#define BB      2048
#define HDIM    300
#define HPAD    320   // K padded to multiple of 32

// aux layout (ints): [16:32) dbase, [32:48) ebase, [64] e15-alloc
#define A_DBASE 16
#define A_EBASE 32
#define A_E15   64

// ---------------- prepack: dst[384][Kpad] = W[k][n]  (B^T panel, zero-padded)
__global__ __launch_bounds__(256) void prepack_w(const float* __restrict__ src,
                                                 _Float16* __restrict__ dst,
                                                 int Kpad, int Kreal) {
    int idx = blockIdx.x * 256 + threadIdx.x;
    int n = idx / Kpad, k = idx - n * Kpad;
    if (n >= 384) return;
    float v = (n < 300 && k < Kreal) ? src[k * 300 + n] : 0.f;
    dst[idx] = (_Float16)v;
}

__global__ __launch_bounds__(256) void cvt_x(const float* __restrict__ x,
                                             _Float16* __restrict__ xh, int n) {
    int i = blockIdx.x * 256 + threadIdx.x;
    if (i < n) xh[i] = (_Float16)x[i];
}

// edge feats -> f16, permuted into CSR order, zero-padded to 32 cols
__global__ __launch_bounds__(256) void cvt_e_csr(const float* __restrict__ ein,
                                                 const int2* __restrict__ se,
                                                 _Float16* __restrict__ ecsr) {
    int i = blockIdx.x * 256 + threadIdx.x;
    if (i >= N_EDGES * 32) return;
    int k = i & 31, s = i >> 5;
    int e = se[s].y;
    ecsr[i] = (_Float16)(k < 16 ? ein[(size_t)e * 16 + k] : 0.f);
}

__device__ __forceinline__ void gload16(const _Float16* g, _Float16* l) {
    __builtin_amdgcn_global_load_lds(
        (const __attribute__((address_space(1))) void*)g,
        (__attribute__((address_space(3))) void*)l, 16, 0, 0);
}

// ---------------- MFMA GEMM: out[M][320] = op( A[M][K] @ Bp^T ) + bias
// Bp is [384][K] f16. 128x128 tile, 4 waves, 64x64/wave.
// global_load_lds staging, 3-buf, single barrier per K-iter, counted vmcnt,
// XOR-swizzled LDS, XCD-grouped blocks, LDS-transposed coalesced epilogue.
template <bool RELU>
__global__ __launch_bounds__(256) void gemm_f16(
        const _Float16* __restrict__ A,
        const _Float16* __restrict__ Bp, const float* __restrict__ bias,
        _Float16* __restrict__ out, int M, int K) {
    __shared__ _Float16 lds[3][2][128 * 32];   // [buf][A/B][row*32+k] : 48 KB

    // XCD grouping: the 3 nt-siblings of one mt land on the same XCD (bid%8)
    int bid = blockIdx.x;
    int xcd = bid & 7, grp = bid >> 3;
    int mt = xcd + 8 * (grp / 3);
    int nt = grp % 3;
    int m0 = mt * 128, n0 = nt * 128;
    int t = threadIdx.x;
    int lane = t & 63, w = t >> 6;
    int wr = w >> 1, wc = w & 1;

    // staging geometry: wave w stages 2 chunks of 16 rows each (1 KB per inst)
    // LDS slot (row, lane&3) <- global chunk (lane&3) ^ ((row>>1)&3)
    int srow[2], sko[2];
    #pragma unroll
    for (int q = 0; q < 2; ++q) {
        int row = (w * 2 + q) * 16 + (lane >> 2);
        int ch = (lane & 3) ^ ((row >> 1) & 3);
        srow[q] = row; sko[q] = ch * 8;
    }

    f32x4 acc[4][4] = {};
    int NK = K >> 5;

    auto stage = [&](int buf, int k0) {
        #pragma unroll
        for (int q = 0; q < 2; ++q) {
            gload16(&A[(size_t)(m0 + srow[q]) * K + k0 + sko[q]], &lds[buf][0][(w * 2 + q) * 512]);
            gload16(&Bp[(size_t)(n0 + srow[q]) * K + k0 + sko[q]], &lds[buf][1][(w * 2 + q) * 512]);
        }
    };

    stage(0, 0);
    if (NK > 1) stage(1, 32);
    for (int kt = 0; kt < NK; ++kt) {
        int cur = kt % 3;
        if (kt + 1 < NK) {
            asm volatile("s_waitcnt vmcnt(4)" ::: "memory");   // stage kt landed
        } else {
            asm volatile("s_waitcnt vmcnt(0)" ::: "memory");
        }
        __builtin_amdgcn_s_barrier();
        __builtin_amdgcn_sched_barrier(0);
        if (kt + 2 < NK) stage((kt + 2) % 3, (kt + 2) << 5);

        int lr = lane & 15, hi = lane >> 4;
        half8 af[4], bf[4];
        #pragma unroll
        for (int i = 0; i < 4; ++i) {
            int row = wr * 64 + i * 16 + lr;
            int lk = (hi ^ ((row >> 1) & 3)) * 8;
            af[i] = *(const half8*)&lds[cur][0][row * 32 + lk];
        }
        #pragma unroll
        for (int j = 0; j < 4; ++j) {
            int row = wc * 64 + j * 16 + lr;
            int lk = (hi ^ ((row >> 1) & 3)) * 8;
            bf[j] = *(const half8*)&lds[cur][1][row * 32 + lk];
        }
        #pragma unroll
        for (int i = 0; i < 4; ++i)
            #pragma unroll
            for (int j = 0; j < 4; ++j)
                acc[i][j] = __builtin_amdgcn_mfma_f32_16x16x32_f16(af[i], bf[j], acc[i][j], 0, 0, 0);
    }
    __syncthreads();   // protect lds reuse by epilogue

    // epilogue: acc -> LDS (f16, 128x128) -> coalesced 256B stores
    _Float16* ct = &lds[0][0][0];
    {
        int lr = lane & 15, lq = (lane >> 4) * 4;
        #pragma unroll
        for (int j = 0; j < 4; ++j) {
            int col = wc * 64 + j * 16 + lr;
            int gcol = n0 + col;
            float bv = (gcol < 300) ? bias[gcol] : 0.f;
            #pragma unroll
            for (int i = 0; i < 4; ++i) {
                int rbase = wr * 64 + i * 16 + lq;
                #pragma unroll
                for (int q = 0; q < 4; ++q) {
                    float v = acc[i][j][q] + bv;
                    if (RELU) v = v > 0.f ? v : 0.f;
                    if (gcol >= 300) v = 0.f;
                    ct[(rbase + q) * 128 + col] = (_Float16)v;
                }
            }
        }
    }
    __syncthreads();
    #pragma unroll
    for (int r = 0; r < 8; ++r) {
        int row = r * 16 + (t >> 4);
        int c8 = (t & 15) * 8;
        if (n0 + c8 < HPAD) {
            half8 v = *(const half8*)&ct[row * 128 + c8];
            *(half8*)&out[(size_t)(m0 + row) * HPAD + n0 + c8] = v;
        }
    }
}

// ---------------- CSR build, degree-sorted, hierarchical (no hot global atomics)
__global__ __launch_bounds__(256) void hist_kernel(const int* __restrict__ dst,
                                                   int* __restrict__ counts) {
    int e = blockIdx.x * 256 + threadIdx.x;
    if (e < N_EDGES) atomicAdd(&counts[dst[e]], 1);
}

// per-block bucket histogram (LDS atomics only) -> bhist[bucket][block]
__global__ __launch_bounds__(256) void bucket_count_block(const int* __restrict__ counts,
                                                          int* __restrict__ bhist) {
    __shared__ int lh[16];
    int blk = blockIdx.x, t = threadIdx.x;
    if (t < 16) lh[t] = 0;
    __syncthreads();
    int deg = counts[blk * 256 + t];
    int b = deg < 15 ? deg : 15;
    atomicAdd(&lh[b], 1);
    __syncthreads();
    if (t < 16) bhist[t * 256 + blk] = lh[t];
}

// exclusive scan of bhist[16*256] (bucket-major) -> sbh; derive dbase/ebase
__global__ __launch_bounds__(256) void scan_bhist(const int* __restrict__ bhist,
                                                  int* __restrict__ sbh,
                                                  int* __restrict__ aux) {
    __shared__ int ps[256];
    int t = threadIdx.x;
    int base = t * 16;
    int vals[16]; int s = 0;
    #pragma unroll
    for (int k = 0; k < 16; ++k) { vals[k] = bhist[base + k]; s += vals[k]; }
    ps[t] = s;
    __syncthreads();
    for (int o = 1; o < 256; o <<= 1) {
        int x = (t >= o) ? ps[t - o] : 0;
        __syncthreads();
        ps[t] += x;
        __syncthreads();
    }
    int ex = ps[t] - s;   // exclusive prefix of this thread's segment
    #pragma unroll
    for (int k = 0; k < 16; ++k) { sbh[base + k] = ex; ex += vals[k]; }
    __syncthreads();
    if (t == 0) {
        int eacc = 0;
        for (int b = 0; b < 16; ++b) {
            int db = sbh[b * 256];
            int dn = (b < 15) ? sbh[(b + 1) * 256] : N_NODES;
            aux[A_DBASE + b] = db;
            aux[A_EBASE + b] = eacc;
            eacc += (dn - db) * b;
        }
    }
}

// place nodes into degree-sorted slots; closed-form r0 (no global return-atomics)
__global__ __launch_bounds__(256) void place2(const int* __restrict__ counts,
                                              const int* __restrict__ sbh,
                                              int* __restrict__ aux,
                                              int* __restrict__ sortedid,
                                              int2* __restrict__ rptr,
                                              int* __restrict__ r0node) {
    __shared__ int lh[16];
    int blk = blockIdx.x, t = threadIdx.x;
    if (t < 16) lh[t] = 0;
    __syncthreads();
    int n = blk * 256 + t;
    int deg = counts[n];
    int b = deg < 15 ? deg : 15;
    int lp = atomicAdd(&lh[b], 1);
    int i = sbh[b * 256 + blk] + lp;
    int r0;
    if (b < 15) r0 = aux[A_EBASE + b] + (i - aux[A_DBASE + b]) * b;
    else        r0 = aux[A_EBASE + 15] + atomicAdd(&aux[A_E15], deg);
    sortedid[i] = n;
    rptr[i] = make_int2(r0, deg);
    r0node[n] = r0;
}

__global__ __launch_bounds__(256) void scatter_csr(const int* __restrict__ src,
                                                   const int* __restrict__ dst,
                                                   const int* __restrict__ r0node,
                                                   int* __restrict__ cnt,
                                                   int2* __restrict__ se) {
    int e = blockIdx.x * 256 + threadIdx.x;
    if (e >= N_EDGES) return;
    int d = dst[e];
    int pos = atomicAdd(&cnt[d], 1);
    se[r0node[d] + pos] = make_int2(src[e], e);
}

// ---------------- gather: z[d] = h[d] + sum_{s in row(d)} relu(h[src_s] + ehcsr[s])
// Nodes processed in degree-sorted order: all node-slots of a wave have equal
// degree -> no trip-count divergence. 320 thr = 8 slots x 40 half8 chunks.
__global__ __launch_bounds__(320) void gather_z(
        const _Float16* __restrict__ h, const _Float16* __restrict__ ehcsr,
        const int2* __restrict__ se, const int* __restrict__ sortedid,
        const int2* __restrict__ rptr, _Float16* __restrict__ z, int nblocks) {
    int t = threadIdx.x;
    int c = t % 40, ns = t / 40;
    for (int i = blockIdx.x * 8 + ns; i < N_NODES; i += nblocks * 8) {
        int node = sortedid[i];
        int2 rr = rptr[i];
        int r0 = rr.x, r1 = rr.x + rr.y;
        half8 hn = *(const half8*)&h[(size_t)node * HPAD + c * 8];
        half8 acc = {};
        for (int s = r0; s < r1; s += 4) {
            int nb = r1 - s;
            int idx[4];
            idx[0] = s;
            idx[1] = s + (1 < nb ? 1 : 0);
            idx[2] = s + (2 < nb ? 2 : 0);
            idx[3] = s + (3 < nb ? 3 : 0);
            half8 hv[4], ev[4];
            #pragma unroll
            for (int u = 0; u < 4; ++u) {
                int sp = se[idx[u]].x;
                hv[u] = *(const half8*)&h[(size_t)sp * HPAD + c * 8];
                ev[u] = *(const half8*)&ehcsr[(size_t)idx[u] * HPAD + c * 8];
            }
            #pragma unroll
            for (int u = 0; u < 4; ++u) {
                half8 m = hv[u] + ev[u];
                #pragma unroll
                for (int j = 0; j < 8; ++j)
                    m[j] = m[j] > (_Float16)0 ? m[j] : (_Float16)0;
                if (u < nb) acc += m;
            }
        }
        half8 o = hn + acc;          // pad cols: 0 + 0 = 0
        *(half8*)&z[(size_t)node * HPAD + c * 8] = o;
    }
}

// ---------------- per-molecule sum pool (32 consecutive rows)
__global__ __launch_bounds__(128) void pool_kernel(const _Float16* __restrict__ h,
                                                   float* __restrict__ out, int add) {
    int b = blockIdx.x, t = threadIdx.x;
    if (t >= 75) return;
    float a0 = 0, a1 = 0, a2 = 0, a3 = 0;
    for (int r = 0; r < 32; ++r) {
        half4 v = *(const half4*)&h[(size_t)(b * 32 + r) * HPAD + t * 4];
        a0 += (float)v[0]; a1 += (float)v[1]; a2 += (float)v[2]; a3 += (float)v[3];
    }
    f32x4 o = {a0, a1, a2, a3};
    if (add) o += *(f32x4*)&out[b * 300 + t * 4];
    *(f32x4*)&out[b * 300 + t * 4] = o;
}

__global__ __launch_bounds__(256) void diff_kernel(float* __restrict__ reaction,
                                                   const float* __restrict__ reactants,
                                                   const float* __restrict__ products, int n) {
    int i = blockIdx.x * 256 + threadIdx.x;
    if (i < n) reaction[i] = reactants[i] - products[i];
}

extern "C" void kernel_launch(void* const* d_in, const int* in_sizes, int n_in,
                              void* d_out, int out_size, void* d_ws, size_t ws_size,
                              hipStream_t stream) {
    const float* x[3]   = {(const float*)d_in[0], (const float*)d_in[5],  (const float*)d_in[10]};
    const float* ein[3] = {(const float*)d_in[1], (const float*)d_in[6],  (const float*)d_in[11]};
    const int*   src[3] = {(const int*)d_in[2],   (const int*)d_in[7],    (const int*)d_in[12]};
    const int*   dst[3] = {(const int*)d_in[3],   (const int*)d_in[8],    (const int*)d_in[13]};
    const float* Wn = (const float*)d_in[15];
    const float* bn = (const float*)d_in[16];
    const float* We = (const float*)d_in[17];
    const float* be = (const float*)d_in[18];
    const float* W1 = (const float*)d_in[19];
    const float* b1 = (const float*)d_in[20];
    const float* W2 = (const float*)d_in[21];
    const float* b2 = (const float*)d_in[22];

    char* ws = (char*)d_ws;
    size_t off = 0;
    auto alloc = [&](size_t bytes) {
        char* p = ws + off; off += (bytes + 1023) & ~(size_t)1023; return p;
    };
    _Float16* h     = (_Float16*)alloc((size_t)N_NODES * HPAD * 2);   // 40 MiB
    _Float16* zbuf  = (_Float16*)alloc((size_t)N_NODES * HPAD * 2);   // 40 MiB
    _Float16* tbuf  = (_Float16*)alloc((size_t)N_NODES * HPAD * 2);   // 40 MiB
    _Float16* ehcsr = (_Float16*)alloc((size_t)N_EDGES * HPAD * 2);   // 80 MiB
    int*      counts= (int*)alloc((size_t)N_NODES * 4);               // \ contiguous
    int*      cnt   = (int*)alloc((size_t)N_NODES * 4);               //  | memset
    int*      aux   = (int*)alloc(256 * 4);                           // /  region
    int*      bhist = (int*)alloc(4096 * 4);
    int*      sbh   = (int*)alloc(4096 * 4);
    int*      sortedid = (int*)alloc((size_t)N_NODES * 4);
    int2*     rptr  = (int2*)alloc((size_t)N_NODES * 8);
    int*      r0node= (int*)alloc((size_t)N_NODES * 4);
    int2*     se    = (int2*)alloc((size_t)N_EDGES * 8);
    _Float16* Wt1   = (_Float16*)alloc((size_t)3 * 384 * HPAD * 2);
    _Float16* Wt2   = (_Float16*)alloc((size_t)3 * 384 * HPAD * 2);
    _Float16* Wnt   = (_Float16*)alloc((size_t)384 * 64 * 2);
    _Float16* Wet   = (_Float16*)alloc((size_t)384 * 32 * 2);
    // overlays (both dead before their hosts are written):
    _Float16* xh    = (_Float16*)zbuf;   // consumed by node-proj GEMM before gather writes zbuf
    _Float16* ecsr  = (_Float16*)tbuf;   // consumed by eh-GEMM before GEMM1 writes tbuf

    if (off > ws_size) return;   // graceful diagnostic failure if ws too small

    for (int l = 0; l < 3; ++l) {
        prepack_w<<<(384 * HPAD + 255) / 256, 256, 0, stream>>>(W1 + l * 90000, Wt1 + l * 384 * HPAD, HPAD, 300);
        prepack_w<<<(384 * HPAD + 255) / 256, 256, 0, stream>>>(W2 + l * 90000, Wt2 + l * 384 * HPAD, HPAD, 300);
    }
    prepack_w<<<(384 * 64 + 255) / 256, 256, 0, stream>>>(Wn, Wnt, 64, 64);
    prepack_w<<<(384 * 32 + 255) / 256, 256, 0, stream>>>(We, Wet, 32, 16);

    float* outp      = (float*)d_out;
    float* reaction  = outp;
    float* reactants = outp + (size_t)BB * HDIM;
    float* products  = outp + (size_t)2 * BB * HDIM;

    const int EG = (N_EDGES + 255) / 256;
    for (int g = 0; g < 3; ++g) {
        // node projection: h = relu(x @ Wn + bn)
        cvt_x<<<(N_NODES * 64 + 255) / 256, 256, 0, stream>>>(x[g], xh, N_NODES * 64);
        gemm_f16<true><<<512 * 3, 256, 0, stream>>>(xh, Wnt, bn, h, N_NODES, 64);

        // degree-sorted CSR build (incoming edges per node), hierarchical
        hipMemsetAsync(counts, 0, (size_t)(2 * N_NODES + 256) * 4, stream);  // counts+cnt+aux
        hist_kernel<<<EG, 256, 0, stream>>>(dst[g], counts);
        bucket_count_block<<<256, 256, 0, stream>>>(counts, bhist);
        scan_bhist<<<1, 256, 0, stream>>>(bhist, sbh, aux);
        place2<<<256, 256, 0, stream>>>(counts, sbh, aux, sortedid, rptr, r0node);
        scatter_csr<<<EG, 256, 0, stream>>>(src[g], dst[g], r0node, cnt, se);

        // edge projection once per graph, in CSR order: ehcsr = ecsr @ We + be
        cvt_e_csr<<<(N_EDGES * 32 + 255) / 256, 256, 0, stream>>>(ein[g], se, ecsr);
        gemm_f16<false><<<1024 * 3, 256, 0, stream>>>(ecsr, Wet, be, ehcsr, N_EDGES, 32);

        for (int l = 0; l < 3; ++l) {
            gather_z<<<2048, 320, 0, stream>>>(h, ehcsr, se, sortedid, rptr, zbuf, 2048);
            // t = relu(z @ W1[l] + b1[l])
            gemm_f16<true><<<512 * 3, 256, 0, stream>>>(zbuf, Wt1 + l * 384 * HPAD, b1 + l * 300, tbuf, N_NODES, HPAD);
            // h = t @ W2[l] + b2[l]  (+relu if l<2)
            if (l < 2)
                gemm_f16<true ><<<512 * 3, 256, 0, stream>>>(tbuf, Wt2 + l * 384 * HPAD, b2 + l * 300, h, N_NODES, HPAD);
            else
                gemm_f16<false><<<512 * 3, 256, 0, stream>>>(tbuf, Wt2 + l * 384 * HPAD, b2 + l * 300, h, N_NODES, HPAD);
        }
        if (g == 0)      pool_kernel<<<BB, 128, 0, stream>>>(h, reactants, 0);
        else if (g == 1) pool_kernel<<<BB, 128, 0, stream>>>(h, reactants, 1);
        else             pool_kernel<<<BB, 128, 0, stream>>>(h, products, 0);
    }
    diff_kernel<<<((BB * HDIM) + 255) / 256, 256, 0, stream>>>(reaction, reactants, products, BB * HDIM);
}